// Round 1
// 127.606 us; speedup vs baseline: 1.0385x; 1.0385x over previous
//
#include <hip/hip_runtime.h>

// Problem constants
#define SRC_N   (512 * 512)
#define IMG_W   1024
#define IMG_HW  (1024 * 1024)
#define BATCH   4

#define CHUNKS_PER_B   128
#define K1_BLOCKS      (BATCH * CHUNKS_PER_B)    // 512
#define K1_THREADS     512
#define PTS_PER_CHUNK  2048
// Bins: 0..255 = 4-row bands (y-interior pixels); 256..287 = row-0 px-segments
// (32 px each); 288..319 = row-1023 px-segments. Corners -> LDS side path.
#define NBINS          320
#define PF_E           (NBINS + 1)               // prefix entries per (b,bin) table
#define SENT           0xFFFFFFFFu

#define EDGE_BLOCKS    (BATCH * 64)              // 256: (b, row{0,1023}, 32px seg)
#define BAND_BLOCKS    (BATCH * 256)             // 1024: (b, 4-row band)

// native vector type for nontemporal builtins (HIP float4 is a class type)
typedef float nfloat4 __attribute__((ext_vector_type(4)));

__device__ __forceinline__ nfloat4 ntload4(const float* p) {
    return __builtin_nontemporal_load((const nfloat4*)p);
}

// ws layout (all tables fully rewritten every call; no memsets needed)
#define STAGED_BYTES ((size_t)K1_BLOCKS * PTS_PER_CHUNK * 16)          // 16 MB
#define PF_OFF       STAGED_BYTES
// prefixT layout: [b][bin(321)][chunk(128)] -> coalesced rs/re reads in K2
#define PF_BYTES     ((size_t)BATCH * PF_E * CHUNKS_PER_B * 4)         // 657 KB
#define CO_OFF       ((PF_OFF + PF_BYTES + 255) & ~(size_t)255)
#define CO_BYTES     ((size_t)K1_BLOCKS * 12 * 4)                      // 24 KB

// ---------------------------------------------------------------------------
// K1: classify + per-chunk bin. Hierarchical scan (wave shfl scan + 8 wave
// totals). Corners accumulate into per-WAVE LDS slots (96 addrs, not 12) to
// cut same-address RMW serialization. Prefix table written TRANSPOSED.
// __launch_bounds__(512,4): cap VGPR<=128 so 2 blocks/CU (16 waves) resident.
// ---------------------------------------------------------------------------
__global__ void __launch_bounds__(512, 4)
bin_kernel(const float* __restrict__ uv, const float* __restrict__ pos,
           float4* __restrict__ staged, unsigned* __restrict__ prefixT,
           float* __restrict__ corner_out) {
    const int blk   = blockIdx.x;          // 0..511
    const int b     = blk >> 7;
    const int chunk = blk & (CHUNKS_PER_B - 1);
    const int t     = threadIdx.x;
    const int lane  = t & 63;
    const int wave  = t >> 6;              // 0..7

    __shared__ unsigned s_hist[512];       // bins 320..511 stay zero
    __shared__ unsigned s_cur[NBINS];
    __shared__ unsigned s_wsum[8];
    __shared__ float    s_corner[96];      // [wave][ci*3+c]

    s_hist[t] = 0;
    if (t < 96) s_corner[t] = 0.0f;
    __syncthreads();                                               // B1

    const float* uvb = uv  + (size_t)b * 14 * SRC_N;
    const float* pb  = pos + (size_t)b * 3  * SRC_N;
    const int n0 = chunk * PTS_PER_CHUNK + t * 4;

    // nontemporal: inputs are read exactly once; keep L2 for the staged buf
    const nfloat4 pxv = ntload4(&pb [n0]);
    const nfloat4 pyv = ntload4(&pb [SRC_N + n0]);
    const nfloat4 ux  = ntload4(&uvb[n0]);
    const nfloat4 uy  = ntload4(&uvb[SRC_N + n0]);
    const nfloat4 ov  = ntload4(&uvb[10 * SRC_N + n0]);
    const nfloat4 rv  = ntload4(&uvb[11 * SRC_N + n0]);
    const nfloat4 gv  = ntload4(&uvb[12 * SRC_N + n0]);
    const nfloat4 bv  = ntload4(&uvb[13 * SRC_N + n0]);

    const float X[4]  = {pxv.x + ux.x, pxv.y + ux.y, pxv.z + ux.z, pxv.w + ux.w};
    const float Y[4]  = {pyv.x + uy.x, pyv.y + uy.y, pyv.z + uy.z, pyv.w + uy.w};
    const float O[4]  = {ov.x, ov.y, ov.z, ov.w};
    const float CR[4] = {rv.x, rv.y, rv.z, rv.w};
    const float CG[4] = {gv.x, gv.y, gv.z, gv.w};
    const float CB[4] = {bv.x, bv.y, bv.z, bv.w};

    unsigned packed[4];
    float R[4], G[4], B[4];

#pragma unroll
    for (int j = 0; j < 4; ++j) {
        // truncating cast (matches .astype(int32)), then clamp
        int px = (int)((X[j] + 1.0f) * 512.0f);
        int py = (int)((Y[j] + 1.0f) * 512.0f);
        px = min(max(px, 0), IMG_W - 1);
        py = min(max(py, 0), IMG_W - 1);

        const float opac = 1.0f / (1.0f + __expf(-O[j]));
        R[j] = CR[j] * opac; G[j] = CG[j] * opac; B[j] = CB[j] * opac;

        const bool xe = (px == 0) | (px == IMG_W - 1);
        const bool ye = (py == 0) | (py == IMG_W - 1);
        if (xe & ye) {
            const int ci = ((py != 0) ? 2 : 0) + ((px != 0) ? 1 : 0);
            const int base = wave * 12 + ci * 3;
            atomicAdd(&s_corner[base + 0], R[j]);
            atomicAdd(&s_corner[base + 1], G[j]);
            atomicAdd(&s_corner[base + 2], B[j]);
            packed[j] = SENT;
        } else {
            int bin;
            if (ye) bin = 256 + ((py != 0) ? 32 : 0) + (px >> 5);  // edge seg
            else    bin = py >> 2;                                 // 4-row band
            atomicAdd(&s_hist[bin], 1u);
            packed[j] = ((unsigned)bin << 12) | ((unsigned)(py & 3) << 10)
                      | (unsigned)px;
        }
    }
    __syncthreads();                                               // B2

    // hierarchical exclusive scan of s_hist[0..511]
    const unsigned h = s_hist[t];
    unsigned incl = h;
#pragma unroll
    for (int off = 1; off < 64; off <<= 1) {
        const unsigned n = __shfl_up(incl, off, 64);
        if (lane >= off) incl += n;
    }
    if (lane == 63) s_wsum[wave] = incl;   // wave total
    __syncthreads();                                               // B3
    unsigned woff = 0;
#pragma unroll
    for (int w = 0; w < 8; ++w) woff += (w < wave) ? s_wsum[w] : 0u;
    const unsigned excl = woff + incl - h;

    if (t < NBINS) s_cur[t] = excl;
    if (t <= NBINS)                        // transposed write: [b][bin][chunk]
        prefixT[((size_t)(b * PF_E + t)) * CHUNKS_PER_B + chunk] = excl;
    if (t < 12) {                          // fold 8 wave corner slots
        float s = 0.0f;
#pragma unroll
        for (int w = 0; w < 8; ++w) s += s_corner[w * 12 + t];
        corner_out[blk * 12 + t] = s;
    }
    __syncthreads();                                               // B4

    // cur-ordered scatter into the chunk's private staged region
    float4* pbase = staged + (size_t)blk * PTS_PER_CHUNK;
#pragma unroll
    for (int j = 0; j < 4; ++j) {
        if (packed[j] != SENT) {
            const int bin = packed[j] >> 12;
            const unsigned p = atomicAdd(&s_cur[bin], 1u);
            pbase[p] = make_float4(__uint_as_float(packed[j]), R[j], G[j], B[j]);
        }
    }
}

// ---------------------------------------------------------------------------
// K2 (merged): blocks [0,256) = edge blocks (b, row in {0,1023}, 32px seg);
// blocks [256,1280) = band blocks (b, 4-row band).
// Rows 0/1023 receive ONLY edge+corner mass (banded py is 1..1022), so edge
// blocks write those output rows directly and band blocks 0/255 skip them —
// no edgebuf, no fold phase, no third kernel.
// Gather: 4 CONSECUTIVE lanes per chunk read the (sorted) run -> 64B
// contiguous per group. rs/re reads are coalesced via the transposed prefix.
// __launch_bounds__(512,6): cap VGPR so the 48KB-LDS 3 blocks/CU is realized.
// ---------------------------------------------------------------------------
__global__ void __launch_bounds__(512, 6)
render_kernel(const float4* __restrict__ staged, const unsigned* __restrict__ prefixT,
              const float* __restrict__ corner_out, float* __restrict__ out) {
    const int t = threadIdx.x;

    __shared__ float    acc[3 * 4096];     // bands: [c][ly*1024+px]; edge: first 96
    __shared__ unsigned rs[128], re[128];
    float4* acc4 = (float4*)acc;

    if (blockIdx.x < EDGE_BLOCKS) {
        const int blk = blockIdx.x;        // b*64 + row*32 + seg
        const int b   = blk >> 6;
        const int row = (blk >> 5) & 1;
        const int seg = blk & 31;
        const int bin = 256 + row * 32 + seg;

        if (t < 96) acc[t] = 0.0f;
        if (t < 128)      rs[t]       = prefixT[((size_t)(b * PF_E + bin)) * 128 + t];
        else if (t < 256) re[t - 128] = prefixT[((size_t)(b * PF_E + bin + 1)) * 128 + (t - 128)];
        __syncthreads();

        const int chunk = t >> 2;
        const int sub   = t & 3;
        const float4* pbase = staged + (size_t)(b * 128 + chunk) * PTS_PER_CHUNK;
        for (unsigned i = rs[chunk] + sub; i < re[chunk]; i += 4) {
            const float4 v = pbase[i];
            const int lx = (int)(__float_as_uint(v.x) & 1023u) - seg * 32;
            atomicAdd(&acc[lx],      v.y);
            atomicAdd(&acc[32 + lx], v.z);
            atomicAdd(&acc[64 + lx], v.w);
        }

        // corner fold: seg 0 owns px=0, seg 31 owns px=1023 of this row
        if (((seg == 0) | (seg == 31)) & (t < 128)) {
            const int ci = row * 2 + ((seg == 31) ? 1 : 0);
            const int lx = (seg == 31) ? 31 : 0;
            const float* cp = corner_out + (size_t)(b * 128 + t) * 12 + ci * 3;
            atomicAdd(&acc[lx],      cp[0]);
            atomicAdd(&acc[32 + lx], cp[1]);
            atomicAdd(&acc[64 + lx], cp[2]);
        }
        __syncthreads();

        if (t < 96) {                      // write final output row directly
            const int c  = t >> 5, lx = t & 31;
            const size_t py = row ? (IMG_W - 1) : 0;
            const float v = acc[c * 32 + lx];
            out[((size_t)b * 3 + c) * IMG_HW + py * IMG_W + seg * 32 + lx] =
                fminf(fmaxf(v, 0.f), 1.f);
        }
        return;
    }

    const int bg   = blockIdx.x - EDGE_BLOCKS;   // 0..1023
    const int b    = bg >> 8;
    const int band = bg & 255;

    const float4 z4 = make_float4(0.f, 0.f, 0.f, 0.f);
#pragma unroll
    for (int i = 0; i < 6; ++i) acc4[i * 512 + t] = z4;
    if (t < 128)      rs[t]       = prefixT[((size_t)(b * PF_E + band)) * 128 + t];
    else if (t < 256) re[t - 128] = prefixT[((size_t)(b * PF_E + band + 1)) * 128 + (t - 128)];
    __syncthreads();

    const int chunk = t >> 2;              // 4 consecutive lanes share a chunk
    const int sub   = t & 3;
    const float4* pbase = staged + (size_t)(b * 128 + chunk) * PTS_PER_CHUNK;
    for (unsigned i = rs[chunk] + sub; i < re[chunk]; i += 4) {
        const float4 v = pbase[i];
        const unsigned key = __float_as_uint(v.x);
        const unsigned idx = ((key >> 10) & 3u) * 1024 + (key & 1023u);
        atomicAdd(&acc[idx],        v.y);
        atomicAdd(&acc[4096 + idx], v.z);
        atomicAdd(&acc[8192 + idx], v.w);
    }
    __syncthreads();

    // linear clipped nontemporal stores; band 0 skips row0, band 255 skips
    // row 1023 (those rows are owned by the edge blocks).
    float* ob = out + (size_t)b * 3 * IMG_HW + (size_t)band * 4096;
    const int skip_ly = (band == 0) ? 0 : ((band == 255) ? 3 : -1);
#pragma unroll
    for (int c = 0; c < 3; ++c) {
        nfloat4* dst = (nfloat4*)(ob + (size_t)c * IMG_HW);
#pragma unroll
        for (int k = 0; k < 2; ++k) {
            const int f = k * 512 + t;           // float4 index within band
            if ((f >> 8) == skip_ly) continue;   // wave-uniform predicate
            float4 v = acc4[c * 1024 + f];
            nfloat4 w;
            w.x = fminf(fmaxf(v.x, 0.f), 1.f);
            w.y = fminf(fmaxf(v.y, 0.f), 1.f);
            w.z = fminf(fmaxf(v.z, 0.f), 1.f);
            w.w = fminf(fmaxf(v.w, 0.f), 1.f);
            __builtin_nontemporal_store(w, &dst[f]);
        }
    }
}

extern "C" void kernel_launch(void* const* d_in, const int* in_sizes, int n_in,
                              void* d_out, int out_size, void* d_ws, size_t ws_size,
                              hipStream_t stream) {
    const float* uv  = (const float*)d_in[0];   // (4,14,512,512)
    const float* pos = (const float*)d_in[1];   // (4,3,512,512)
    float* out = (float*)d_out;                 // (4,3,1024,1024)

    char* ws = (char*)d_ws;
    float4*   staged     = (float4*)(ws);
    unsigned* prefixT    = (unsigned*)(ws + PF_OFF);
    float*    corner_out = (float*)(ws + CO_OFF);

    bin_kernel   <<<K1_BLOCKS, K1_THREADS, 0, stream>>>(uv, pos, staged, prefixT,
                                                        corner_out);
    render_kernel<<<EDGE_BLOCKS + BAND_BLOCKS, 512, 0, stream>>>(staged, prefixT,
                                                                 corner_out, out);
}

// Round 3
// 124.891 us; speedup vs baseline: 1.0611x; 1.0217x over previous
//
#include <hip/hip_runtime.h>

// Problem constants
#define SRC_N   (512 * 512)
#define IMG_W   1024
#define IMG_HW  (1024 * 1024)
#define BATCH   4

#define CHUNKS_PER_B   128
#define K1_BLOCKS      (BATCH * CHUNKS_PER_B)    // 512
#define K1_THREADS     512
#define PTS_PER_CHUNK  2048
// Bins: 0..255 = 4-row bands (y-interior pixels); 256..287 = row-0 px-segments
// (32 px each); 288..319 = row-1023 px-segments. Corners -> LDS side path.
#define NBINS          320
#define PF_E           (NBINS + 1)               // prefix entries per (b,bin) table
#define SENT           0xFFFFFFFFu

#define EDGE_BLOCKS    (BATCH * 64)              // 256: (b, row{0,1023}, 32px seg)
#define BAND_BLOCKS    (BATCH * 256)             // 1024: (b, 4-row band)

// native vector type for nontemporal builtins (HIP float4 is a class type)
typedef float nfloat4 __attribute__((ext_vector_type(4)));

__device__ __forceinline__ nfloat4 ntload4(const float* p) {
    return __builtin_nontemporal_load((const nfloat4*)p);
}

// ws layout (all tables fully rewritten every call; no memsets needed)
#define STAGED_BYTES ((size_t)K1_BLOCKS * PTS_PER_CHUNK * 16)          // 16 MB
#define PF_OFF       STAGED_BYTES
// prefixT layout: [b][bin(321)][chunk(128)] -> coalesced rs/re reads in K2
#define PF_BYTES     ((size_t)BATCH * PF_E * CHUNKS_PER_B * 4)         // 657 KB
#define CO_OFF       ((PF_OFF + PF_BYTES + 255) & ~(size_t)255)
#define CO_BYTES     ((size_t)K1_BLOCKS * 12 * 4)                      // 24 KB

// ---------------------------------------------------------------------------
// K1: classify + per-chunk bin. Hierarchical scan (wave shfl scan + 8 wave
// totals). Corners accumulate into per-WAVE LDS slots. Prefix table written
// TRANSPOSED. Scatter lands in a 32KB LDS staging buffer (scattered ds_write
// is cheap), then a fully COALESCED linear copy LDS->global replaces the
// previous scattered 16B global stores (~4x transaction inflation).
// Stores are regular (not NT) so K2 reads hit L2.
// LDS total ~35.7KB -> still 2 blocks/CU at VGPR<=128 (launch_bounds 512,4).
// ---------------------------------------------------------------------------
__global__ void __launch_bounds__(512, 4)
bin_kernel(const float* __restrict__ uv, const float* __restrict__ pos,
           float4* __restrict__ staged, unsigned* __restrict__ prefixT,
           float* __restrict__ corner_out) {
    const int blk   = blockIdx.x;          // 0..511
    const int b     = blk >> 7;
    const int chunk = blk & (CHUNKS_PER_B - 1);
    const int t     = threadIdx.x;
    const int lane  = t & 63;
    const int wave  = t >> 6;              // 0..7

    __shared__ unsigned s_hist[512];       // bins 320..511 stay zero
    __shared__ unsigned s_cur[NBINS];
    __shared__ unsigned s_wsum[8];
    __shared__ float    s_corner[96];      // [wave][ci*3+c]
    __shared__ float4   s_stage[PTS_PER_CHUNK];   // 32KB bin-sorted staging

    s_hist[t] = 0;
    if (t < 96) s_corner[t] = 0.0f;
    __syncthreads();                                               // B1

    const float* uvb = uv  + (size_t)b * 14 * SRC_N;
    const float* pb  = pos + (size_t)b * 3  * SRC_N;
    const int n0 = chunk * PTS_PER_CHUNK + t * 4;

    // nontemporal: inputs are read exactly once; keep L2 for the staged buf
    const nfloat4 pxv = ntload4(&pb [n0]);
    const nfloat4 pyv = ntload4(&pb [SRC_N + n0]);
    const nfloat4 ux  = ntload4(&uvb[n0]);
    const nfloat4 uy  = ntload4(&uvb[SRC_N + n0]);
    const nfloat4 ov  = ntload4(&uvb[10 * SRC_N + n0]);
    const nfloat4 rv  = ntload4(&uvb[11 * SRC_N + n0]);
    const nfloat4 gv  = ntload4(&uvb[12 * SRC_N + n0]);
    const nfloat4 bv  = ntload4(&uvb[13 * SRC_N + n0]);

    const float X[4]  = {pxv.x + ux.x, pxv.y + ux.y, pxv.z + ux.z, pxv.w + ux.w};
    const float Y[4]  = {pyv.x + uy.x, pyv.y + uy.y, pyv.z + uy.z, pyv.w + uy.w};
    const float O[4]  = {ov.x, ov.y, ov.z, ov.w};
    const float CR[4] = {rv.x, rv.y, rv.z, rv.w};
    const float CG[4] = {gv.x, gv.y, gv.z, gv.w};
    const float CB[4] = {bv.x, bv.y, bv.z, bv.w};

    unsigned packed[4];
    float R[4], G[4], B[4];

#pragma unroll
    for (int j = 0; j < 4; ++j) {
        // truncating cast (matches .astype(int32)), then clamp
        int px = (int)((X[j] + 1.0f) * 512.0f);
        int py = (int)((Y[j] + 1.0f) * 512.0f);
        px = min(max(px, 0), IMG_W - 1);
        py = min(max(py, 0), IMG_W - 1);

        const float opac = 1.0f / (1.0f + __expf(-O[j]));
        R[j] = CR[j] * opac; G[j] = CG[j] * opac; B[j] = CB[j] * opac;

        const bool xe = (px == 0) | (px == IMG_W - 1);
        const bool ye = (py == 0) | (py == IMG_W - 1);
        if (xe & ye) {
            const int ci = ((py != 0) ? 2 : 0) + ((px != 0) ? 1 : 0);
            const int base = wave * 12 + ci * 3;
            atomicAdd(&s_corner[base + 0], R[j]);
            atomicAdd(&s_corner[base + 1], G[j]);
            atomicAdd(&s_corner[base + 2], B[j]);
            packed[j] = SENT;
        } else {
            int bin;
            if (ye) bin = 256 + ((py != 0) ? 32 : 0) + (px >> 5);  // edge seg
            else    bin = py >> 2;                                 // 4-row band
            atomicAdd(&s_hist[bin], 1u);
            packed[j] = ((unsigned)bin << 12) | ((unsigned)(py & 3) << 10)
                      | (unsigned)px;
        }
    }
    __syncthreads();                                               // B2

    // hierarchical exclusive scan of s_hist[0..511]
    const unsigned h = s_hist[t];
    unsigned incl = h;
#pragma unroll
    for (int off = 1; off < 64; off <<= 1) {
        const unsigned n = __shfl_up(incl, off, 64);
        if (lane >= off) incl += n;
    }
    if (lane == 63) s_wsum[wave] = incl;   // wave total
    __syncthreads();                                               // B3
    unsigned woff = 0;
#pragma unroll
    for (int w = 0; w < 8; ++w) woff += (w < wave) ? s_wsum[w] : 0u;
    const unsigned excl = woff + incl - h;

    if (t < NBINS) s_cur[t] = excl;
    if (t <= NBINS)                        // transposed write: [b][bin][chunk]
        prefixT[((size_t)(b * PF_E + t)) * CHUNKS_PER_B + chunk] = excl;
    if (t < 12) {                          // fold 8 wave corner slots
        float s = 0.0f;
#pragma unroll
        for (int w = 0; w < 8; ++w) s += s_corner[w * 12 + t];
        corner_out[blk * 12 + t] = s;
    }
    __syncthreads();                                               // B4

    // cur-ordered scatter into LDS staging (scattered ds_write_b128: cheap)
#pragma unroll
    for (int j = 0; j < 4; ++j) {
        if (packed[j] != SENT) {
            const int bin = packed[j] >> 12;
            const unsigned p = atomicAdd(&s_cur[bin], 1u);
            s_stage[p] = make_float4(__uint_as_float(packed[j]), R[j], G[j], B[j]);
        }
    }
    __syncthreads();                                               // B5

    // fully coalesced LDS -> global copy (1KB per wave per step)
    float4* pbase = staged + (size_t)blk * PTS_PER_CHUNK;
#pragma unroll
    for (int k = 0; k < 4; ++k)
        pbase[k * 512 + t] = s_stage[k * 512 + t];
}

// ---------------------------------------------------------------------------
// K2 (merged): blocks [0,256) = edge blocks (b, row in {0,1023}, 32px seg);
// blocks [256,1280) = band blocks (b, 4-row band).
// Rows 0/1023 receive ONLY edge+corner mass (banded py is 1..1022), so edge
// blocks write those output rows directly and band blocks 0/255 skip them.
// Gather: 4 CONSECUTIVE lanes per chunk read the (sorted) run -> 64B
// contiguous per group. rs/re reads are coalesced via the transposed prefix.
// __launch_bounds__(512,6): cap VGPR so the 48KB-LDS 3 blocks/CU is realized.
// ---------------------------------------------------------------------------
__global__ void __launch_bounds__(512, 6)
render_kernel(const float4* __restrict__ staged, const unsigned* __restrict__ prefixT,
              const float* __restrict__ corner_out, float* __restrict__ out) {
    const int t = threadIdx.x;

    __shared__ float    acc[3 * 4096];     // bands: [c][ly*1024+px]; edge: first 96
    __shared__ unsigned rs[128], re[128];
    float4* acc4 = (float4*)acc;

    if (blockIdx.x < EDGE_BLOCKS) {
        const int blk = blockIdx.x;        // b*64 + row*32 + seg
        const int b   = blk >> 6;
        const int row = (blk >> 5) & 1;
        const int seg = blk & 31;
        const int bin = 256 + row * 32 + seg;

        if (t < 96) acc[t] = 0.0f;
        if (t < 128)      rs[t]       = prefixT[((size_t)(b * PF_E + bin)) * 128 + t];
        else if (t < 256) re[t - 128] = prefixT[((size_t)(b * PF_E + bin + 1)) * 128 + (t - 128)];
        __syncthreads();

        const int chunk = t >> 2;
        const int sub   = t & 3;
        const float4* pbase = staged + (size_t)(b * 128 + chunk) * PTS_PER_CHUNK;
        for (unsigned i = rs[chunk] + sub; i < re[chunk]; i += 4) {
            const float4 v = pbase[i];
            const int lx = (int)(__float_as_uint(v.x) & 1023u) - seg * 32;
            atomicAdd(&acc[lx],      v.y);
            atomicAdd(&acc[32 + lx], v.z);
            atomicAdd(&acc[64 + lx], v.w);
        }

        // corner fold: seg 0 owns px=0, seg 31 owns px=1023 of this row
        if (((seg == 0) | (seg == 31)) & (t < 128)) {
            const int ci = row * 2 + ((seg == 31) ? 1 : 0);
            const int lx = (seg == 31) ? 31 : 0;
            const float* cp = corner_out + (size_t)(b * 128 + t) * 12 + ci * 3;
            atomicAdd(&acc[lx],      cp[0]);
            atomicAdd(&acc[32 + lx], cp[1]);
            atomicAdd(&acc[64 + lx], cp[2]);
        }
        __syncthreads();

        if (t < 96) {                      // write final output row directly
            const int c  = t >> 5, lx = t & 31;
            const size_t py = row ? (IMG_W - 1) : 0;
            const float v = acc[c * 32 + lx];
            out[((size_t)b * 3 + c) * IMG_HW + py * IMG_W + seg * 32 + lx] =
                fminf(fmaxf(v, 0.f), 1.f);
        }
        return;
    }

    const int bg   = blockIdx.x - EDGE_BLOCKS;   // 0..1023
    const int b    = bg >> 8;
    const int band = bg & 255;

    const float4 z4 = make_float4(0.f, 0.f, 0.f, 0.f);
#pragma unroll
    for (int i = 0; i < 6; ++i) acc4[i * 512 + t] = z4;
    if (t < 128)      rs[t]       = prefixT[((size_t)(b * PF_E + band)) * 128 + t];
    else if (t < 256) re[t - 128] = prefixT[((size_t)(b * PF_E + band + 1)) * 128 + (t - 128)];
    __syncthreads();

    const int chunk = t >> 2;              // 4 consecutive lanes share a chunk
    const int sub   = t & 3;
    const float4* pbase = staged + (size_t)(b * 128 + chunk) * PTS_PER_CHUNK;
    for (unsigned i = rs[chunk] + sub; i < re[chunk]; i += 4) {
        const float4 v = pbase[i];
        const unsigned key = __float_as_uint(v.x);
        const unsigned idx = ((key >> 10) & 3u) * 1024 + (key & 1023u);
        atomicAdd(&acc[idx],        v.y);
        atomicAdd(&acc[4096 + idx], v.z);
        atomicAdd(&acc[8192 + idx], v.w);
    }
    __syncthreads();

    // linear clipped nontemporal stores; band 0 skips row0, band 255 skips
    // row 1023 (those rows are owned by the edge blocks).
    float* ob = out + (size_t)b * 3 * IMG_HW + (size_t)band * 4096;
    const int skip_ly = (band == 0) ? 0 : ((band == 255) ? 3 : -1);
#pragma unroll
    for (int c = 0; c < 3; ++c) {
        nfloat4* dst = (nfloat4*)(ob + (size_t)c * IMG_HW);
#pragma unroll
        for (int k = 0; k < 2; ++k) {
            const int f = k * 512 + t;           // float4 index within band
            if ((f >> 8) == skip_ly) continue;   // wave-uniform predicate
            float4 v = acc4[c * 1024 + f];
            nfloat4 w;
            w.x = fminf(fmaxf(v.x, 0.f), 1.f);
            w.y = fminf(fmaxf(v.y, 0.f), 1.f);
            w.z = fminf(fmaxf(v.z, 0.f), 1.f);
            w.w = fminf(fmaxf(v.w, 0.f), 1.f);
            __builtin_nontemporal_store(w, &dst[f]);
        }
    }
}

extern "C" void kernel_launch(void* const* d_in, const int* in_sizes, int n_in,
                              void* d_out, int out_size, void* d_ws, size_t ws_size,
                              hipStream_t stream) {
    const float* uv  = (const float*)d_in[0];   // (4,14,512,512)
    const float* pos = (const float*)d_in[1];   // (4,3,512,512)
    float* out = (float*)d_out;                 // (4,3,1024,1024)

    char* ws = (char*)d_ws;
    float4*   staged     = (float4*)(ws);
    unsigned* prefixT    = (unsigned*)(ws + PF_OFF);
    float*    corner_out = (float*)(ws + CO_OFF);

    bin_kernel   <<<K1_BLOCKS, K1_THREADS, 0, stream>>>(uv, pos, staged, prefixT,
                                                        corner_out);
    render_kernel<<<EDGE_BLOCKS + BAND_BLOCKS, 512, 0, stream>>>(staged, prefixT,
                                                                 corner_out, out);
}